// Round 12
// baseline (158.204 us; speedup 1.0000x reference)
//
#include <hip/hip_runtime.h>
#include <hip/hip_bf16.h>
#include <math.h>

#define B_  2
#define S_  2048
#define D_  1024
#define H_  16
#define DH_ 64
#define M_  (B_ * S_)   // 4096 tokens

typedef __attribute__((ext_vector_type(8))) short bf16x8;   // 8 bf16 (4 VGPRs)
typedef __attribute__((ext_vector_type(16))) float f32x16;  // 32x32 MFMA C/D
typedef __attribute__((ext_vector_type(2))) unsigned u32x2;

__device__ __forceinline__ float fast_exp2(float x) {
  return __builtin_amdgcn_exp2f(x);   // v_exp_f32
}

__device__ __forceinline__ unsigned short f2bf(float f) {
  union { float f; unsigned u; } c; c.f = f;
  unsigned u = c.u;
  return (unsigned short)((u + 0x7FFFu + ((u >> 16) & 1u)) >> 16);  // RNE
}

// pack two floats -> one dword of 2 bf16 via HW cvt (1 VALU instr)
__device__ __forceinline__ unsigned cvtpk(float lo, float hi) {
  unsigned r;
  asm("v_cvt_pk_bf16_f32 %0, %1, %2" : "=v"(r) : "v"(lo), "v"(hi));
  return r;
}

// T12: swap upper 32 lanes of x with lower 32 lanes of y (both updated)
__device__ __forceinline__ void plswap(unsigned &x, unsigned &y) {
  u32x2 r = __builtin_amdgcn_permlane32_swap(x, y, false, false);
  x = r[0]; y = r[1];
}

__device__ __forceinline__ float logsig(float x) {
  // stable log_sigmoid; __logf ok: e in (0,1], result feeds bf16 anyway
  const float e = __expf(-fabsf(x));
  return fminf(x, 0.f) - __logf(1.f + e);
}

// ---------------------------------------------------------------------------
// Kernel 0: transpose Wq/Wk (fp32 [K][N]) -> bf16 W^T [N][K]
// ---------------------------------------------------------------------------
__global__ __launch_bounds__(256) void prep_w(
    const float* __restrict__ Wq, const float* __restrict__ Wk,
    unsigned short* __restrict__ WqT, unsigned short* __restrict__ WkT)
{
  __shared__ unsigned short T[64][72];
  const int tid = threadIdx.x;
  const int k0 = blockIdx.x * 64;
  const int n0 = blockIdx.y * 64;
  const float* W = blockIdx.z ? Wk : Wq;
  unsigned short* WT = blockIdx.z ? WkT : WqT;

  const int kr = tid >> 2, nc = (tid & 3) * 16;
  #pragma unroll
  for (int i = 0; i < 4; i++) {
    const float4 v = *(const float4*)&W[(size_t)(k0 + kr) * D_ + n0 + nc + i * 4];
    T[nc + i * 4 + 0][kr] = f2bf(v.x);
    T[nc + i * 4 + 1][kr] = f2bf(v.y);
    T[nc + i * 4 + 2][kr] = f2bf(v.z);
    T[nc + i * 4 + 3][kr] = f2bf(v.w);
  }
  __syncthreads();
  const int nr = tid >> 2, kc = (tid & 3) * 16;
  const uint4 a = *(const uint4*)&T[nr][kc];
  const uint4 b = *(const uint4*)&T[nr][kc + 8];
  *(uint4*)&WT[(size_t)(n0 + nr) * D_ + k0 + kc] = a;
  *(uint4*)&WT[(size_t)(n0 + nr) * D_ + k0 + kc + 8] = b;
}

// ---------------------------------------------------------------------------
// Kernel 1: Q = hs@Wq+bq ; K2 = logsig(logsig(Q)+Q+hs@Wk+bk)
// Round-12: CONSOLIDATE to 1 block/CU (the verified r6 attn move). Block
// 256m x 64n, 1024 threads, 16 waves = (msel = w&7 -> 32m, nsel = w>>3 ->
// 32n). Grid 16x16 = 256 blocks = 1/CU; per-CU B-staging traffic and
// barrier count HALVE; occupancy stays 4 waves/SIMD. 32x32x16 MFMA + C/D
// map HW-verified (r8/r11). Epilogue: direct ushort4 QT stores (contiguous
// 64B runs per row; QT/K2b live in L2/L3 — WRITE_SIZE shows only `out`
// reaches HBM). 2-barrier + T14 skeleton verbatim from r9/r11.
// LDS: Ash 36K + Bsh 18K = 54 KB.
// ---------------------------------------------------------------------------
__global__ __launch_bounds__(1024) void proj_kernel(
    const float* __restrict__ hs,
    const unsigned short* __restrict__ WqT, const unsigned short* __restrict__ WkT,
    const float* __restrict__ bqv, const float* __restrict__ bkv,
    unsigned short* __restrict__ K2b, unsigned short* __restrict__ QT)
{
  __shared__ unsigned short Ash[256][72];     // hs tile [m][k] (bf16)
  __shared__ unsigned short Bsh[2][64][72];   // W^T tiles [n][k]

  const int tid  = threadIdx.x;
  const int w    = tid >> 6;          // 0..15
  const int lane = tid & 63;
  const int r31  = lane & 31;
  const int hi   = lane >> 5;
  const int hi8  = hi * 8;
  const int msel = w & 7;             // 32-m group within 256
  const int nsel = w >> 3;            // 32-n group within 64
  const int m0 = blockIdx.x * 256;
  const int n0 = blockIdx.y * 64;     // = head * 64

  const int n_loc = nsel * 32 + r31;
  const float bqs = bqv[n0 + n_loc];
  const float bks = bkv[n0 + n_loc];

  f32x16 accQ, accK;
  #pragma unroll
  for (int r = 0; r < 16; r++) { accQ[r] = 0.f; accK[r] = 0.f; }

  const int am = tid >> 2, ac = (tid & 3) * 16;   // A: 256 rows, 16 fp32/thread
  const int bn = tid >> 4, bc = (tid & 15) * 4;   // B: 64 rows, 4 bf16/thread/mat

  // ---- preload K-tile 0 into registers (T14 issue-early) ----
  float4 Af[4];
  uint2 Bq, Bk;
  {
    const size_t ra = (size_t)(m0 + am) * D_ + ac;
    #pragma unroll
    for (int i = 0; i < 4; i++) Af[i] = *(const float4*)&hs[ra + i * 4];
    const size_t rb = (size_t)(n0 + bn) * D_ + bc;
    Bq = *(const uint2*)&WqT[rb];
    Bk = *(const uint2*)&WkT[rb];
  }

  for (int k0 = 0; k0 < D_; k0 += 64) {
    if (k0) __syncthreads();   // all waves done reading the previous tile
    // stage tile k0 from registers; fp32 A converted to bf16 here
    {
      uint4 t0, t1;
      t0.x = cvtpk(Af[0].x, Af[0].y);  t0.y = cvtpk(Af[0].z, Af[0].w);
      t0.z = cvtpk(Af[1].x, Af[1].y);  t0.w = cvtpk(Af[1].z, Af[1].w);
      t1.x = cvtpk(Af[2].x, Af[2].y);  t1.y = cvtpk(Af[2].z, Af[2].w);
      t1.z = cvtpk(Af[3].x, Af[3].y);  t1.w = cvtpk(Af[3].z, Af[3].w);
      *(uint4*)&Ash[am][ac]     = t0;
      *(uint4*)&Ash[am][ac + 8] = t1;
    }
    *(uint2*)&Bsh[0][bn][bc] = Bq;
    *(uint2*)&Bsh[1][bn][bc] = Bk;
    __syncthreads();           // staged

    // issue tile k0+64's global loads NOW; they drain during compute
    if (k0 + 64 < D_) {
      const size_t ra = (size_t)(m0 + am) * D_ + (k0 + 64) + ac;
      #pragma unroll
      for (int i = 0; i < 4; i++) Af[i] = *(const float4*)&hs[ra + i * 4];
      const size_t rb = (size_t)(n0 + bn) * D_ + (k0 + 64) + bc;
      Bq = *(const uint2*)&WqT[rb];
      Bk = *(const uint2*)&WkT[rb];
    }

    // 32x32x16 compute: K = 64 in 4 steps, A = hs m-rows, B = W^T n-rows
    __builtin_amdgcn_s_setprio(1);
    #pragma unroll
    for (int s = 0; s < 4; s++) {
      const bf16x8 af  = *(const bf16x8*)&Ash[msel * 32 + r31][s * 16 + hi8];
      const bf16x8 bqf = *(const bf16x8*)&Bsh[0][nsel * 32 + r31][s * 16 + hi8];
      const bf16x8 bkf = *(const bf16x8*)&Bsh[1][nsel * 32 + r31][s * 16 + hi8];
      accQ = __builtin_amdgcn_mfma_f32_32x32x16_bf16(af, bqf, accQ, 0, 0, 0);
      accK = __builtin_amdgcn_mfma_f32_32x32x16_bf16(af, bkf, accK, 0, 0, 0);
    }
    __builtin_amdgcn_s_setprio(0);
  }

  // epilogue: bias + logsigmoid chain; K2 row-major stores; QT direct stores
  // (no LDS reuse -> no barrier needed). reg r -> m = (r&3)+8*(r>>2)+4*hi.
  float qv[16];
  #pragma unroll
  for (int r = 0; r < 16; r++) {
    const float q  = accQ[r] + bqs;
    const float kr = accK[r] + bks;
    const float k2 = logsig(logsig(q) + q + kr);
    const int m = m0 + msel * 32 + (r & 3) + 8 * (r >> 2) + 4 * hi;
    K2b[(size_t)m * D_ + n0 + n_loc] = f2bf(k2);
    qv[r] = q;
  }
  #pragma unroll
  for (int rq = 0; rq < 4; rq++) {
    const ushort4 qu = {f2bf(qv[4*rq]), f2bf(qv[4*rq+1]),
                        f2bf(qv[4*rq+2]), f2bf(qv[4*rq+3])};
    *(ushort4*)&QT[(size_t)(n0 + n_loc) * M_ + m0 + msel * 32 + rq * 8 + 4 * hi] = qu;
  }
}

// ---------------------------------------------------------------------------
// Kernel 2: flash attention, S^T formulation, FIXED-SHIFT softmax.
//   s2 = c2 * sc (exp2 domain); p = exp2(s2 - 12). Shift-invariance makes a
//   constant shift exact; no max-reduce, no rescale — and key-split partials
//   (unnormalized O, row-sum l) combine EXACTLY by addition.
// Round-12: KVBLK 64 -> 128. Same 2-barrier-per-stage skeleton; barrier
// count halves (32 -> 16); inner body = verified r9 compute x2 (sub = 0,1)
// with key offsets sub*64. Staging one uint4/thread per matrix. Geometry,
// T12 in-register P, key-split combine verbatim from r9/r11.
// LDS: Qa 36K + K2s[128][72] 18K + Vt[64][136] 17.4K = 72.7 KB, 1 block/CU.
// ---------------------------------------------------------------------------
__global__ __launch_bounds__(1024) void attn_kernel(
    const unsigned short* __restrict__ QT,
    const unsigned short* __restrict__ K2b,
    const int* __restrict__ mask,
    float* __restrict__ out)
{
  __shared__ unsigned short Qa [256][72];   // Q [q][d], col-swizzled
  __shared__ unsigned short K2s[128][72];   // K2 [key][d]
  __shared__ unsigned short Vt [64][136];   // V^T [d][key]

  const int tid  = threadIdx.x;
  const int w    = tid >> 6;           // 0..15
  const int lane = tid & 63;
  const int r31  = lane & 31;          // A-frag row / q column
  const int hi   = lane >> 5;
  const int hi8  = hi * 8;
  const int qsub = w & 7;              // which 32-q group
  const int ksel = w >> 3;             // which 32-key half of each 64-key sub

  const int qt = blockIdx.x;           // 0..7
  const int bh = blockIdx.y;           // 0..31
  const int b = bh >> 4, h = bh & 15;
  const size_t qrow0 = (size_t)b * S_ + (size_t)qt * 256;
  const size_t krow0 = (size_t)b * S_;
  const size_t trow  = (size_t)h * 64;

  // ---- preload K/V tile 0 (128 keys) into registers (T14 issue-early) ----
  const int krr = tid >> 3, kcc = (tid & 7) * 8;    // K2: 128 rows x 64 d
  const int vrr = tid >> 4, vcc = (tid & 15) * 8;   // V^T: 64 d x 128 keys
  uint4 kreg, vreg;
  kreg = *(const uint4*)&K2b[(krow0 + krr) * D_ + trow + kcc];
  vreg = *(const uint4*)&QT [(trow + vrr) * M_ + krow0 + vcc];

  // ---- stage Qa [256 q][64 d], swizzled cols (verbatim r6) ----
  {
    const int dr = tid >> 4, qg = tid & 15;
    const int qc = qg * 16;
    const int dcol = dr ^ ((qg & 7) << 3);
    #pragma unroll
    for (int i = 0; i < 2; i++) {
      const uint4 v = *(const uint4*)&QT[(trow + dr) * M_ + qrow0 + qc + i * 8];
      const unsigned short* p = (const unsigned short*)&v;
      #pragma unroll
      for (int j = 0; j < 8; j++) Qa[qc + i * 8 + j][dcol] = p[j];
    }
  }
  __syncthreads();

  // hoist Q B-frags: frag s covers d = s*16 + hi*8 + j
  bf16x8 qfrag[4];
  {
    const int qrow = qsub * 32 + r31;
    const int g7 = (qrow >> 4) & 7;     // stored-col swizzle group (per-lane)
    #pragma unroll
    for (int s = 0; s < 4; s++)
      qfrag[s] = *(const bf16x8*)&Qa[qrow][(s * 16 + hi8) ^ (g7 << 3)];
  }

  // c2 = -(1/8)*log2(e)*msk ; fixed shift of 12 in exp2 domain
  const float c2 = (mask[qrow0 + qsub * 32 + r31] != 0) ? -0.18033688f : 0.f;
  float rl = 0.f;

  f32x16 Ot0, Ot1;
  #pragma unroll
  for (int r = 0; r < 16; r++) { Ot0[r] = 0.f; Ot1[r] = 0.f; }

  const int NT = S_ / 128;   // 16 stages of 128 keys
  for (int kt = 0; kt < NT; kt++) {
    __syncthreads();   // all waves done reading LDS of stage kt-1
    *(uint4*)&K2s[krr][kcc] = kreg;
    *(uint4*)&Vt [vrr][vcc] = vreg;
    __syncthreads();   // staged

    // T14: issue stage kt+1's global loads NOW; they drain during compute
    if (kt + 1 < NT) {
      kreg = *(const uint4*)&K2b[(krow0 + (kt + 1) * 128 + krr) * D_ + trow + kcc];
      vreg = *(const uint4*)&QT [(trow + vrr) * M_ + krow0 + (kt + 1) * 128 + vcc];
    }

    #pragma unroll
    for (int sub = 0; sub < 2; sub++) {
      const int kb = sub * 64;

      // QK^T: S^T[key][q] for this wave's 32 keys x 32 q, K = 64 d, 4 steps
      bf16x8 kf[4];
      #pragma unroll
      for (int s = 0; s < 4; s++)
        kf[s] = *(const bf16x8*)&K2s[kb + ksel * 32 + r31][s * 16 + hi8];
      f32x16 sc;
      #pragma unroll
      for (int r = 0; r < 16; r++) sc[r] = 0.f;
      __builtin_amdgcn_s_setprio(1);
      #pragma unroll
      for (int s = 0; s < 4; s++)
        sc = __builtin_amdgcn_mfma_f32_32x32x16_bf16(kf[s], qfrag[s], sc, 0, 0, 0);
      __builtin_amdgcn_s_setprio(0);

      // p = exp2(c2*sc - 12); row-sum; T12 in-register P fragments
      float p[16];
      #pragma unroll
      for (int r = 0; r < 16; r++) p[r] = fast_exp2(fmaf(sc[r], c2, -12.f));
      #pragma unroll
      for (int r = 0; r < 16; r += 4) rl += ((p[r] + p[r+1]) + (p[r+2] + p[r+3]));

      unsigned pk0 = cvtpk(p[0],  p[1]),  pk1 = cvtpk(p[2],  p[3]);
      unsigned pk2 = cvtpk(p[4],  p[5]),  pk3 = cvtpk(p[6],  p[7]);
      unsigned pk4 = cvtpk(p[8],  p[9]),  pk5 = cvtpk(p[10], p[11]);
      unsigned pk6 = cvtpk(p[12], p[13]), pk7 = cvtpk(p[14], p[15]);
      plswap(pk0, pk2);   // pk0 -> dword0 (k01|k89), pk2 -> dword2 (k45|k12,13)
      plswap(pk1, pk3);
      plswap(pk4, pk6);
      plswap(pk5, pk7);
      union { unsigned d[8]; bf16x8 v[2]; } pu;
      pu.d[0] = pk0; pu.d[1] = pk1; pu.d[2] = pk2; pu.d[3] = pk3;
      pu.d[4] = pk4; pu.d[5] = pk5; pu.d[6] = pk6; pu.d[7] = pk7;

      // PV: O^T[d][q] partial over own 32 keys (2 k-steps x 2 d-blocks)
      __builtin_amdgcn_s_setprio(1);
      #pragma unroll
      for (int s2 = 0; s2 < 2; s2++) {
        const bf16x8 pf  = pu.v[s2];
        const bf16x8 vf0 = *(const bf16x8*)&Vt[r31]     [kb + ksel * 32 + s2 * 16 + hi8];
        const bf16x8 vf1 = *(const bf16x8*)&Vt[32 + r31][kb + ksel * 32 + s2 * 16 + hi8];
        Ot0 = __builtin_amdgcn_mfma_f32_32x32x16_bf16(vf0, pf, Ot0, 0, 0, 0);
        Ot1 = __builtin_amdgcn_mfma_f32_32x32x16_bf16(vf1, pf, Ot1, 0, 0, 0);
      }
      __builtin_amdgcn_s_setprio(0);
    }
  }

  // ---- key-split combine: exact (no rescale ever happened) ----
  rl += __shfl_xor(rl, 32);               // q-sum over this wave's 32 keys
  __syncthreads();                         // loop LDS reads all done; reuse Qa/K2s
  float* redO = (float*)&Qa[0][0];         // [8 qsub][16 reg][64 lane] = 32 KB
  float* redL = (float*)&K2s[0][0];        // [8 qsub][64 lane] = 2 KB
  if (ksel == 1) {
    #pragma unroll
    for (int r = 0; r < 16; r++) redO[(qsub * 16 + r) * 64 + lane] = Ot0[r];
    redL[qsub * 64 + lane] = rl;
  }
  __syncthreads();
  float inv = 0.f;
  size_t orow = 0;
  if (ksel == 0) {
    const float lt = rl + redL[qsub * 64 + lane];
    inv = 1.f / fmaxf(lt, 1e-35f);
    orow = (qrow0 + qsub * 32 + r31) * D_ + trow;
    #pragma unroll
    for (int rq = 0; rq < 4; rq++) {       // regs 4rq..4rq+3 -> d = 8rq+4hi+0..3
      float4 o;
      o.x = (Ot0[4*rq+0] + redO[(qsub*16 + 4*rq+0)*64 + lane]) * inv;
      o.y = (Ot0[4*rq+1] + redO[(qsub*16 + 4*rq+1)*64 + lane]) * inv;
      o.z = (Ot0[4*rq+2] + redO[(qsub*16 + 4*rq+2)*64 + lane]) * inv;
      o.w = (Ot0[4*rq+3] + redO[(qsub*16 + 4*rq+3)*64 + lane]) * inv;
      *(float4*)&out[orow + rq * 8 + 4 * hi] = o;
    }
  }
  __syncthreads();
  if (ksel == 1) {
    #pragma unroll
    for (int r = 0; r < 16; r++) redO[(qsub * 16 + r) * 64 + lane] = Ot1[r];
  }
  __syncthreads();
  if (ksel == 0) {
    #pragma unroll
    for (int rq = 0; rq < 4; rq++) {
      float4 o;
      o.x = (Ot1[4*rq+0] + redO[(qsub*16 + 4*rq+0)*64 + lane]) * inv;
      o.y = (Ot1[4*rq+1] + redO[(qsub*16 + 4*rq+1)*64 + lane]) * inv;
      o.z = (Ot1[4*rq+2] + redO[(qsub*16 + 4*rq+2)*64 + lane]) * inv;
      o.w = (Ot1[4*rq+3] + redO[(qsub*16 + 4*rq+3)*64 + lane]) * inv;
      *(float4*)&out[orow + 32 + rq * 8 + 4 * hi] = o;
    }
  }
}

extern "C" void kernel_launch(void* const* d_in, const int* in_sizes, int n_in,
                              void* d_out, int out_size, void* d_ws, size_t ws_size,
                              hipStream_t stream) {
  const float* hs  = (const float*)d_in[0];
  const int*   msk = (const int*)d_in[1];
  const float* Wq  = (const float*)d_in[2];
  const float* bq  = (const float*)d_in[3];
  const float* Wk  = (const float*)d_in[4];
  const float* bk  = (const float*)d_in[5];
  float* out = (float*)d_out;

  unsigned short* QT  = (unsigned short*)d_ws;             // [H*64][M_]  8 MB
  unsigned short* K2b = QT  + (size_t)D_ * M_;             // [M_][D_]    8 MB
  unsigned short* WqT = K2b + (size_t)M_ * D_;             // [D_][D_]    2 MB
  unsigned short* WkT = WqT + (size_t)D_ * D_;             // [D_][D_]    2 MB

  prep_w<<<dim3(D_ / 64, D_ / 64, 2), 256, 0, stream>>>(Wq, Wk, WqT, WkT);
  proj_kernel<<<dim3(M_ / 256, D_ / 64), 1024, 0, stream>>>(hs, WqT, WkT, bq, bk, K2b, QT);
  attn_kernel<<<dim3(S_ / 256, B_ * H_), 1024, 0, stream>>>(QT, K2b, msk, out);
}

// Round 13
// 148.634 us; speedup vs baseline: 1.0644x; 1.0644x over previous
//
#include <hip/hip_runtime.h>
#include <hip/hip_bf16.h>
#include <math.h>

#define B_  2
#define S_  2048
#define D_  1024
#define H_  16
#define DH_ 64
#define M_  (B_ * S_)   // 4096 tokens

typedef __attribute__((ext_vector_type(8))) short bf16x8;   // 8 bf16 (4 VGPRs)
typedef __attribute__((ext_vector_type(16))) float f32x16;  // 32x32 MFMA C/D
typedef __attribute__((ext_vector_type(2))) unsigned u32x2;

__device__ __forceinline__ float fast_exp2(float x) {
  return __builtin_amdgcn_exp2f(x);   // v_exp_f32
}

__device__ __forceinline__ unsigned short f2bf(float f) {
  union { float f; unsigned u; } c; c.f = f;
  unsigned u = c.u;
  return (unsigned short)((u + 0x7FFFu + ((u >> 16) & 1u)) >> 16);  // RNE
}

// pack two floats -> one dword of 2 bf16 via HW cvt (1 VALU instr)
__device__ __forceinline__ unsigned cvtpk(float lo, float hi) {
  unsigned r;
  asm("v_cvt_pk_bf16_f32 %0, %1, %2" : "=v"(r) : "v"(lo), "v"(hi));
  return r;
}

// T12: swap upper 32 lanes of x with lower 32 lanes of y (both updated)
__device__ __forceinline__ void plswap(unsigned &x, unsigned &y) {
  u32x2 r = __builtin_amdgcn_permlane32_swap(x, y, false, false);
  x = r[0]; y = r[1];
}

__device__ __forceinline__ float logsig(float x) {
  // stable log_sigmoid; __logf ok: e in (0,1], result feeds bf16 anyway
  const float e = __expf(-fabsf(x));
  return fminf(x, 0.f) - __logf(1.f + e);
}

// ---------------------------------------------------------------------------
// Kernel 0: transpose Wq/Wk (fp32 [K][N]) -> bf16 W^T [N][K]
// ---------------------------------------------------------------------------
__global__ __launch_bounds__(256) void prep_w(
    const float* __restrict__ Wq, const float* __restrict__ Wk,
    unsigned short* __restrict__ WqT, unsigned short* __restrict__ WkT)
{
  __shared__ unsigned short T[64][72];
  const int tid = threadIdx.x;
  const int k0 = blockIdx.x * 64;
  const int n0 = blockIdx.y * 64;
  const float* W = blockIdx.z ? Wk : Wq;
  unsigned short* WT = blockIdx.z ? WkT : WqT;

  const int kr = tid >> 2, nc = (tid & 3) * 16;
  #pragma unroll
  for (int i = 0; i < 4; i++) {
    const float4 v = *(const float4*)&W[(size_t)(k0 + kr) * D_ + n0 + nc + i * 4];
    T[nc + i * 4 + 0][kr] = f2bf(v.x);
    T[nc + i * 4 + 1][kr] = f2bf(v.y);
    T[nc + i * 4 + 2][kr] = f2bf(v.z);
    T[nc + i * 4 + 3][kr] = f2bf(v.w);
  }
  __syncthreads();
  const int nr = tid >> 2, kc = (tid & 3) * 16;
  const uint4 a = *(const uint4*)&T[nr][kc];
  const uint4 b = *(const uint4*)&T[nr][kc + 8];
  *(uint4*)&WT[(size_t)(n0 + nr) * D_ + k0 + kc] = a;
  *(uint4*)&WT[(size_t)(n0 + nr) * D_ + k0 + kc + 8] = b;
}

// ---------------------------------------------------------------------------
// Kernel 1: Q = hs@Wq+bq ; K2 = logsig(logsig(Q)+Q+hs@Wk+bk)
// (verbatim verified round 11 — its fastest form. r12's 1-block/CU +
//  direct-QT-scatter-store variant REVERTED: the 64-lane 8B-store scatter
//  at 8KB stride regressed proj ~6 us. 512 thr / 8 waves, 128m x 64n,
//  32x32x16 MFMA, 2-barrier + T14 skeleton, Qt LDS-transpose epilogue.)
// ---------------------------------------------------------------------------
__global__ __launch_bounds__(512, 4) void proj_kernel(
    const float* __restrict__ hs,
    const unsigned short* __restrict__ WqT, const unsigned short* __restrict__ WkT,
    const float* __restrict__ bqv, const float* __restrict__ bkv,
    unsigned short* __restrict__ K2b, unsigned short* __restrict__ QT)
{
  __shared__ unsigned short Ash[128][72];     // hs tile [m][k] (bf16)
  __shared__ unsigned short Bsh[2][64][72];   // W^T tiles [n][k]

  const int tid  = threadIdx.x;
  const int w    = tid >> 6;          // 0..7
  const int lane = tid & 63;
  const int r31  = lane & 31;
  const int hi   = lane >> 5;
  const int hi8  = hi * 8;
  const int msel = w & 3;             // 32-m group within 128
  const int nsel = w >> 2;            // 32-n group within 64
  const int m0 = blockIdx.x * 128;
  const int n0 = blockIdx.y * 64;     // = head * 64

  const int n_loc = nsel * 32 + r31;
  const float bqs = bqv[n0 + n_loc];
  const float bks = bkv[n0 + n_loc];

  f32x16 accQ, accK;
  #pragma unroll
  for (int r = 0; r < 16; r++) { accQ[r] = 0.f; accK[r] = 0.f; }

  const int am = tid >> 2, ac = (tid & 3) * 16;   // A: 128 rows, 16 fp32/thread
  const int bn = tid >> 3, bc = (tid & 7) * 8;    // B: 64 rows, 8 bf16/thread/mat

  // ---- preload K-tile 0 into registers (T14 issue-early) ----
  float4 Af[4];
  uint4 Bq, Bk;
  {
    const size_t ra = (size_t)(m0 + am) * D_ + ac;
    #pragma unroll
    for (int i = 0; i < 4; i++) Af[i] = *(const float4*)&hs[ra + i * 4];
    const size_t rb = (size_t)(n0 + bn) * D_ + bc;
    Bq = *(const uint4*)&WqT[rb];
    Bk = *(const uint4*)&WkT[rb];
  }

  for (int k0 = 0; k0 < D_; k0 += 64) {
    if (k0) __syncthreads();   // all waves done reading the previous tile
    // stage tile k0 from registers; fp32 A converted to bf16 here
    {
      uint4 t0, t1;
      t0.x = cvtpk(Af[0].x, Af[0].y);  t0.y = cvtpk(Af[0].z, Af[0].w);
      t0.z = cvtpk(Af[1].x, Af[1].y);  t0.w = cvtpk(Af[1].z, Af[1].w);
      t1.x = cvtpk(Af[2].x, Af[2].y);  t1.y = cvtpk(Af[2].z, Af[2].w);
      t1.z = cvtpk(Af[3].x, Af[3].y);  t1.w = cvtpk(Af[3].z, Af[3].w);
      *(uint4*)&Ash[am][ac]     = t0;
      *(uint4*)&Ash[am][ac + 8] = t1;
    }
    *(uint4*)&Bsh[0][bn][bc] = Bq;
    *(uint4*)&Bsh[1][bn][bc] = Bk;
    __syncthreads();           // staged

    // issue tile k0+64's global loads NOW; they drain during compute
    if (k0 + 64 < D_) {
      const size_t ra = (size_t)(m0 + am) * D_ + (k0 + 64) + ac;
      #pragma unroll
      for (int i = 0; i < 4; i++) Af[i] = *(const float4*)&hs[ra + i * 4];
      const size_t rb = (size_t)(n0 + bn) * D_ + (k0 + 64) + bc;
      Bq = *(const uint4*)&WqT[rb];
      Bk = *(const uint4*)&WkT[rb];
    }

    // 32x32x16 compute: K = 64 in 4 steps, A = hs m-rows, B = W^T n-rows
    __builtin_amdgcn_s_setprio(1);
    #pragma unroll
    for (int s = 0; s < 4; s++) {
      const bf16x8 af  = *(const bf16x8*)&Ash[msel * 32 + r31][s * 16 + hi8];
      const bf16x8 bqf = *(const bf16x8*)&Bsh[0][nsel * 32 + r31][s * 16 + hi8];
      const bf16x8 bkf = *(const bf16x8*)&Bsh[1][nsel * 32 + r31][s * 16 + hi8];
      accQ = __builtin_amdgcn_mfma_f32_32x32x16_bf16(af, bqf, accQ, 0, 0, 0);
      accK = __builtin_amdgcn_mfma_f32_32x32x16_bf16(af, bkf, accK, 0, 0, 0);
    }
    __builtin_amdgcn_s_setprio(0);
  }
  __syncthreads();   // protect epilogue's reuse of Bsh as Qt

  // epilogue: bias + logsigmoid chain; K2 row-major stores; Q -> LDS transpose
  unsigned short* Qt = &Bsh[0][0][0];   // 64*136 = 8704 shorts <= 9216 avail
  float qv[16];
  #pragma unroll
  for (int r = 0; r < 16; r++) {
    const float q  = accQ[r] + bqs;
    const float kr = accK[r] + bks;
    const float k2 = logsig(logsig(q) + q + kr);
    const int m = m0 + msel * 32 + (r & 3) + 8 * (r >> 2) + 4 * hi;
    K2b[(size_t)m * D_ + n0 + n_loc] = f2bf(k2);
    qv[r] = q;
  }
  #pragma unroll
  for (int rq = 0; rq < 4; rq++) {
    const ushort4 qu = {f2bf(qv[4*rq]), f2bf(qv[4*rq+1]),
                        f2bf(qv[4*rq+2]), f2bf(qv[4*rq+3])};
    *(ushort4*)&Qt[n_loc * 136 + msel * 32 + rq * 8 + 4 * hi] = qu;
  }
  __syncthreads();
  {
    const int dr = tid >> 3, mc = (tid & 7) * 16;
    #pragma unroll
    for (int i = 0; i < 2; i++) {
      const uint4 v = *(const uint4*)&Qt[dr * 136 + mc + i * 8];
      *(uint4*)&QT[(size_t)(n0 + dr) * M_ + m0 + mc + i * 8] = v;
    }
  }
}

// ---------------------------------------------------------------------------
// Kernel 2: flash attention, S^T formulation, FIXED-SHIFT softmax.
//   s2 = c2 * sc (exp2 domain); p = exp2(s2 - 12). Shift-invariance makes a
//   constant shift exact; no max-reduce, no rescale — and key-split partials
//   (unnormalized O, row-sum l) combine EXACTLY by addition.
// Round-13: + T1 XCD-aware block swizzle. Old mapping put the 8 qt-blocks
// of one (b,h) on 8 DIFFERENT XCDs (round-robin by linear id) -> each XCD
// re-fetched the full 512KB K/V slice past its private L2 (FETCH 68.6MB vs
// ~20MB unique). New mapping: lid = x + 8y; bh = (lid&7) + 8*(lid>>6),
// qt = (lid>>3)&7  (bijective) -> ids = c (mod 8) give XCD c four complete
// bh-groups (2MB K/V <= 4MB L2). Rest verbatim verified r12 (KVBLK=128).
// LDS: Qa 36K + K2s[128][72] 18K + Vt[64][136] 17.4K = 72.7 KB, 1 block/CU.
// ---------------------------------------------------------------------------
__global__ __launch_bounds__(1024) void attn_kernel(
    const unsigned short* __restrict__ QT,
    const unsigned short* __restrict__ K2b,
    const int* __restrict__ mask,
    float* __restrict__ out)
{
  __shared__ unsigned short Qa [256][72];   // Q [q][d], col-swizzled
  __shared__ unsigned short K2s[128][72];   // K2 [key][d]
  __shared__ unsigned short Vt [64][136];   // V^T [d][key]

  const int tid  = threadIdx.x;
  const int w    = tid >> 6;           // 0..15
  const int lane = tid & 63;
  const int r31  = lane & 31;          // A-frag row / q column
  const int hi   = lane >> 5;
  const int hi8  = hi * 8;
  const int qsub = w & 7;              // which 32-q group
  const int ksel = w >> 3;             // which 32-key half of each 64-key sub

  // T1 XCD swizzle: same-bh blocks -> same XCD (see header comment)
  const int lid = blockIdx.x + 8 * blockIdx.y;   // grid (8, 32)
  const int bh  = (lid & 7) + 8 * (lid >> 6);    // 0..31
  const int qt  = (lid >> 3) & 7;                // 0..7
  const int b = bh >> 4, h = bh & 15;
  const size_t qrow0 = (size_t)b * S_ + (size_t)qt * 256;
  const size_t krow0 = (size_t)b * S_;
  const size_t trow  = (size_t)h * 64;

  // ---- preload K/V tile 0 (128 keys) into registers (T14 issue-early) ----
  const int krr = tid >> 3, kcc = (tid & 7) * 8;    // K2: 128 rows x 64 d
  const int vrr = tid >> 4, vcc = (tid & 15) * 8;   // V^T: 64 d x 128 keys
  uint4 kreg, vreg;
  kreg = *(const uint4*)&K2b[(krow0 + krr) * D_ + trow + kcc];
  vreg = *(const uint4*)&QT [(trow + vrr) * M_ + krow0 + vcc];

  // ---- stage Qa [256 q][64 d], swizzled cols (verbatim r6) ----
  {
    const int dr = tid >> 4, qg = tid & 15;
    const int qc = qg * 16;
    const int dcol = dr ^ ((qg & 7) << 3);
    #pragma unroll
    for (int i = 0; i < 2; i++) {
      const uint4 v = *(const uint4*)&QT[(trow + dr) * M_ + qrow0 + qc + i * 8];
      const unsigned short* p = (const unsigned short*)&v;
      #pragma unroll
      for (int j = 0; j < 8; j++) Qa[qc + i * 8 + j][dcol] = p[j];
    }
  }
  __syncthreads();

  // hoist Q B-frags: frag s covers d = s*16 + hi*8 + j
  bf16x8 qfrag[4];
  {
    const int qrow = qsub * 32 + r31;
    const int g7 = (qrow >> 4) & 7;     // stored-col swizzle group (per-lane)
    #pragma unroll
    for (int s = 0; s < 4; s++)
      qfrag[s] = *(const bf16x8*)&Qa[qrow][(s * 16 + hi8) ^ (g7 << 3)];
  }

  // c2 = -(1/8)*log2(e)*msk ; fixed shift of 12 in exp2 domain
  const float c2 = (mask[qrow0 + qsub * 32 + r31] != 0) ? -0.18033688f : 0.f;
  float rl = 0.f;

  f32x16 Ot0, Ot1;
  #pragma unroll
  for (int r = 0; r < 16; r++) { Ot0[r] = 0.f; Ot1[r] = 0.f; }

  const int NT = S_ / 128;   // 16 stages of 128 keys
  for (int kt = 0; kt < NT; kt++) {
    __syncthreads();   // all waves done reading LDS of stage kt-1
    *(uint4*)&K2s[krr][kcc] = kreg;
    *(uint4*)&Vt [vrr][vcc] = vreg;
    __syncthreads();   // staged

    // T14: issue stage kt+1's global loads NOW; they drain during compute
    if (kt + 1 < NT) {
      kreg = *(const uint4*)&K2b[(krow0 + (kt + 1) * 128 + krr) * D_ + trow + kcc];
      vreg = *(const uint4*)&QT [(trow + vrr) * M_ + krow0 + (kt + 1) * 128 + vcc];
    }

    #pragma unroll
    for (int sub = 0; sub < 2; sub++) {
      const int kb = sub * 64;

      // QK^T: S^T[key][q] for this wave's 32 keys x 32 q, K = 64 d, 4 steps
      bf16x8 kf[4];
      #pragma unroll
      for (int s = 0; s < 4; s++)
        kf[s] = *(const bf16x8*)&K2s[kb + ksel * 32 + r31][s * 16 + hi8];
      f32x16 sc;
      #pragma unroll
      for (int r = 0; r < 16; r++) sc[r] = 0.f;
      __builtin_amdgcn_s_setprio(1);
      #pragma unroll
      for (int s = 0; s < 4; s++)
        sc = __builtin_amdgcn_mfma_f32_32x32x16_bf16(kf[s], qfrag[s], sc, 0, 0, 0);
      __builtin_amdgcn_s_setprio(0);

      // p = exp2(c2*sc - 12); row-sum; T12 in-register P fragments
      float p[16];
      #pragma unroll
      for (int r = 0; r < 16; r++) p[r] = fast_exp2(fmaf(sc[r], c2, -12.f));
      #pragma unroll
      for (int r = 0; r < 16; r += 4) rl += ((p[r] + p[r+1]) + (p[r+2] + p[r+3]));

      unsigned pk0 = cvtpk(p[0],  p[1]),  pk1 = cvtpk(p[2],  p[3]);
      unsigned pk2 = cvtpk(p[4],  p[5]),  pk3 = cvtpk(p[6],  p[7]);
      unsigned pk4 = cvtpk(p[8],  p[9]),  pk5 = cvtpk(p[10], p[11]);
      unsigned pk6 = cvtpk(p[12], p[13]), pk7 = cvtpk(p[14], p[15]);
      plswap(pk0, pk2);   // pk0 -> dword0 (k01|k89), pk2 -> dword2 (k45|k12,13)
      plswap(pk1, pk3);
      plswap(pk4, pk6);
      plswap(pk5, pk7);
      union { unsigned d[8]; bf16x8 v[2]; } pu;
      pu.d[0] = pk0; pu.d[1] = pk1; pu.d[2] = pk2; pu.d[3] = pk3;
      pu.d[4] = pk4; pu.d[5] = pk5; pu.d[6] = pk6; pu.d[7] = pk7;

      // PV: O^T[d][q] partial over own 32 keys (2 k-steps x 2 d-blocks)
      __builtin_amdgcn_s_setprio(1);
      #pragma unroll
      for (int s2 = 0; s2 < 2; s2++) {
        const bf16x8 pf  = pu.v[s2];
        const bf16x8 vf0 = *(const bf16x8*)&Vt[r31]     [kb + ksel * 32 + s2 * 16 + hi8];
        const bf16x8 vf1 = *(const bf16x8*)&Vt[32 + r31][kb + ksel * 32 + s2 * 16 + hi8];
        Ot0 = __builtin_amdgcn_mfma_f32_32x32x16_bf16(vf0, pf, Ot0, 0, 0, 0);
        Ot1 = __builtin_amdgcn_mfma_f32_32x32x16_bf16(vf1, pf, Ot1, 0, 0, 0);
      }
      __builtin_amdgcn_s_setprio(0);
    }
  }

  // ---- key-split combine: exact (no rescale ever happened) ----
  rl += __shfl_xor(rl, 32);               // q-sum over this wave's 32 keys
  __syncthreads();                         // loop LDS reads all done; reuse Qa/K2s
  float* redO = (float*)&Qa[0][0];         // [8 qsub][16 reg][64 lane] = 32 KB
  float* redL = (float*)&K2s[0][0];        // [8 qsub][64 lane] = 2 KB
  if (ksel == 1) {
    #pragma unroll
    for (int r = 0; r < 16; r++) redO[(qsub * 16 + r) * 64 + lane] = Ot0[r];
    redL[qsub * 64 + lane] = rl;
  }
  __syncthreads();
  float inv = 0.f;
  size_t orow = 0;
  if (ksel == 0) {
    const float lt = rl + redL[qsub * 64 + lane];
    inv = 1.f / fmaxf(lt, 1e-35f);
    orow = (qrow0 + qsub * 32 + r31) * D_ + trow;
    #pragma unroll
    for (int rq = 0; rq < 4; rq++) {       // regs 4rq..4rq+3 -> d = 8rq+4hi+0..3
      float4 o;
      o.x = (Ot0[4*rq+0] + redO[(qsub*16 + 4*rq+0)*64 + lane]) * inv;
      o.y = (Ot0[4*rq+1] + redO[(qsub*16 + 4*rq+1)*64 + lane]) * inv;
      o.z = (Ot0[4*rq+2] + redO[(qsub*16 + 4*rq+2)*64 + lane]) * inv;
      o.w = (Ot0[4*rq+3] + redO[(qsub*16 + 4*rq+3)*64 + lane]) * inv;
      *(float4*)&out[orow + rq * 8 + 4 * hi] = o;
    }
  }
  __syncthreads();
  if (ksel == 1) {
    #pragma unroll
    for (int r = 0; r < 16; r++) redO[(qsub * 16 + r) * 64 + lane] = Ot1[r];
  }
  __syncthreads();
  if (ksel == 0) {
    #pragma unroll
    for (int rq = 0; rq < 4; rq++) {
      float4 o;
      o.x = (Ot1[4*rq+0] + redO[(qsub*16 + 4*rq+0)*64 + lane]) * inv;
      o.y = (Ot1[4*rq+1] + redO[(qsub*16 + 4*rq+1)*64 + lane]) * inv;
      o.z = (Ot1[4*rq+2] + redO[(qsub*16 + 4*rq+2)*64 + lane]) * inv;
      o.w = (Ot1[4*rq+3] + redO[(qsub*16 + 4*rq+3)*64 + lane]) * inv;
      *(float4*)&out[orow + 32 + rq * 8 + 4 * hi] = o;
    }
  }
}

extern "C" void kernel_launch(void* const* d_in, const int* in_sizes, int n_in,
                              void* d_out, int out_size, void* d_ws, size_t ws_size,
                              hipStream_t stream) {
  const float* hs  = (const float*)d_in[0];
  const int*   msk = (const int*)d_in[1];
  const float* Wq  = (const float*)d_in[2];
  const float* bq  = (const float*)d_in[3];
  const float* Wk  = (const float*)d_in[4];
  const float* bk  = (const float*)d_in[5];
  float* out = (float*)d_out;

  unsigned short* QT  = (unsigned short*)d_ws;             // [H*64][M_]  8 MB
  unsigned short* K2b = QT  + (size_t)D_ * M_;             // [M_][D_]    8 MB
  unsigned short* WqT = K2b + (size_t)M_ * D_;             // [D_][D_]    2 MB
  unsigned short* WkT = WqT + (size_t)D_ * D_;             // [D_][D_]    2 MB

  prep_w<<<dim3(D_ / 64, D_ / 64, 2), 256, 0, stream>>>(Wq, Wk, WqT, WkT);
  proj_kernel<<<dim3(M_ / 128, D_ / 64), 512, 0, stream>>>(hs, WqT, WkT, bq, bk, K2b, QT);
  attn_kernel<<<dim3(S_ / 256, B_ * H_), 1024, 0, stream>>>(QT, K2b, msk, out);
}